// Round 1
// baseline (406.465 us; speedup 1.0000x reference)
//
#include <hip/hip_runtime.h>
#include <math.h>

// Problem constants (from reference setup_inputs):
//   x, noise: (b=16, t=8, c=32, h=64, w=64) float32, values in [0,16)
//   epoch: int scalar
#define B_   16
#define T_   8
#define C_   32
#define HW_  4096            // h*w
#define K_   16              // value bins
#define CHW_ (C_*HW_)        // 131072: stride between consecutive t for fixed (b,c)
#define BC_  (B_*C_)         // 512 samples per spatial element
#define P_BLK 16             // spatial positions per workgroup (64B coalescing)

typedef unsigned int uint;

// ---------------------------------------------------------------------------
// Kernel A: per-element joint histograms (t vs t=0) + MI, and accumulate the
// pooled (global) histograms via atomics.
// Grid: HW_/P_BLK = 256 blocks, 256 threads.
// LDS: hist[8][16][256] u32 = 128KB  +  log table 513 f64 = 4.1KB.
// MI identity used:  MI = ln(n) + ( Σ c·ln c  −  Σ_a r_a·ln r_a  −  Σ_v col_v·ln col_v ) / n
// (all counts are integers ≤ 512 → exact LDS log table, no per-cell marginals)
// ---------------------------------------------------------------------------
__global__ __launch_bounds__(256) void k_hist_mi(const float* __restrict__ x,
                                                 uint* __restrict__ glob_hist,
                                                 double* __restrict__ ele) {
  __shared__ uint   hist[T_][P_BLK][256];
  __shared__ double logtab[513];

  const int tid = threadIdx.x;
  const int p0  = blockIdx.x * P_BLK;

  for (int i = tid; i < T_ * P_BLK * 256; i += 256) ((uint*)hist)[i] = 0u;
  for (int i = tid; i < 513; i += 256) logtab[i] = (i > 0) ? log((double)i) : 0.0;
  __syncthreads();

  const int lp = tid & 15;   // which p within the block  (coalesced lanes)
  const int g  = tid >> 4;   // sample-group 0..15

  #pragma unroll 2
  for (int bc = g; bc < BC_; bc += 16) {
    const int b = bc >> 5;
    const int c = bc & 31;
    const float* base = x + ((b * T_) * C_ + c) * HW_ + p0 + lp;  // t=0 address
    const int a   = (int)base[0];      // s0 value (row index)
    const int row = a << 4;
    atomicAdd(&hist[0][lp][row + a], 1u);   // t=0: joint(a,a)
    #pragma unroll
    for (int t = 1; t < T_; ++t) {
      const int v = (int)base[t * CHW_];
      atomicAdd(&hist[t][lp][row + v], 1u);
    }
  }
  __syncthreads();

  // Pooled histograms: global joint = sum over p of per-element joints.
  for (int i = tid; i < T_ * 256; i += 256) {
    const int t = i >> 8, bin = i & 255;
    uint s = 0;
    #pragma unroll
    for (int p = 0; p < P_BLK; ++p) s += hist[t][p][bin];
    atomicAdd(&glob_hist[i], s);
  }

  // Per-element MI: one thread per (t, p) — 128 active threads.
  if (tid < T_ * P_BLK) {
    const int t   = tid >> 4;
    const int lpp = tid & 15;
    const uint* h = &hist[t][lpp][0];
    double term = 0.0;
    #pragma unroll
    for (int a = 0; a < K_; ++a) {
      uint r = 0;
      #pragma unroll
      for (int v = 0; v < K_; ++v) {
        const uint cnt = h[(a << 4) + v];
        r += cnt;
        term += (double)cnt * logtab[cnt];      // c·ln c  (logtab[0]=0)
      }
      term -= (double)r * logtab[r];            // r·ln r   (r ≤ 512)
    }
    #pragma unroll
    for (int v = 0; v < K_; ++v) {
      uint col = 0;
      #pragma unroll
      for (int a = 0; a < K_; ++a) col += h[(a << 4) + v];
      term -= (double)col * logtab[col];        // col·ln col
    }
    // MI = ln(512) + term/512
    ele[t * HW_ + p0 + lpp] = logtab[512] + term * (1.0 / 512.0);
  }
}

// ---------------------------------------------------------------------------
// Kernel B: global MI per t (8 tiny MI evals, n = 2^21), then
// prob[t][p] = clip( (ele[t][p]*glob[t]) / (ele[0][p]*glob[0]) * epoch/200, 0, 1 ),
// prob[0][*] = 0.   One block, 256 threads.
// ---------------------------------------------------------------------------
__global__ __launch_bounds__(256) void k_glob_prob(const uint* __restrict__ glob_hist,
                                                   const double* __restrict__ ele,
                                                   const int* __restrict__ epoch_ptr,
                                                   float* __restrict__ prob) {
  __shared__ double glob[T_];
  const int tid = threadIdx.x;

  if (tid < T_) {
    const uint* h = glob_hist + tid * 256;
    double term = 0.0;
    for (int a = 0; a < K_; ++a) {
      double r = 0.0;
      for (int v = 0; v < K_; ++v) {
        const double cnt = (double)h[(a << 4) + v];
        r += cnt;
        if (cnt > 0.0) term += cnt * log(cnt);
      }
      if (r > 0.0) term -= r * log(r);
    }
    for (int v = 0; v < K_; ++v) {
      double col = 0.0;
      for (int a = 0; a < K_; ++a) col += (double)h[(a << 4) + v];
      if (col > 0.0) term -= col * log(col);
    }
    const double n = (double)BC_ * (double)HW_;   // 2097152
    glob[tid] = log(n) + term / n;
  }
  __syncthreads();

  const double escale = (double)(*epoch_ptr) * (1.0 / 200.0);

  for (int i = tid; i < T_ * HW_; i += 256) {
    const int t = i >> 12;
    const int p = i & (HW_ - 1);
    float pv;
    if (t == 0) {
      pv = 0.0f;                       // reference: mi.at[0].set(0) → prob row 0 = 0
    } else {
      const double mi0 = ele[p] * glob[0];
      const double mit = ele[i] * glob[t];
      double v = (mit / mi0) * escale;
      pv = fminf(fmaxf((float)v, 0.0f), 1.0f);
    }
    prob[i] = pv;
  }
}

// ---------------------------------------------------------------------------
// Kernel C: out = (noise < prob[t][p]) ? 0 : x.  float4 vectorized, 1 elem4/thread.
// t constant within a float4 (HW_ % 4 == 0), prob read as aligned float4.
// ---------------------------------------------------------------------------
__global__ __launch_bounds__(256) void k_mask(const float4* __restrict__ x4,
                                              const float4* __restrict__ n4,
                                              const float* __restrict__ prob,
                                              float4* __restrict__ o4) {
  const int i = blockIdx.x * 256 + threadIdx.x;        // float4 index, < 4194304
  const int t = (i >> 15) & 7;                         // (4i / 131072) % 8
  const float4 pr = ((const float4*)prob)[(t << 10) | (i & 1023)];
  const float4 xv = x4[i];
  const float4 nv = n4[i];
  float4 o;
  o.x = (nv.x < pr.x) ? 0.0f : xv.x;
  o.y = (nv.y < pr.y) ? 0.0f : xv.y;
  o.z = (nv.z < pr.z) ? 0.0f : xv.z;
  o.w = (nv.w < pr.w) ? 0.0f : xv.w;
  o4[i] = o;
}

// ---------------------------------------------------------------------------
// Workspace layout:
//   [0, 8KB)            glob_hist : u32[8][256]          (memset to 0 each call)
//   [8KB, 8KB+256KB)    ele       : f64[8][4096]
//   [+256KB, +128KB)    prob      : f32[8][4096]
// ---------------------------------------------------------------------------
extern "C" void kernel_launch(void* const* d_in, const int* in_sizes, int n_in,
                              void* d_out, int out_size, void* d_ws, size_t ws_size,
                              hipStream_t stream) {
  const float* x     = (const float*)d_in[0];
  const float* noise = (const float*)d_in[1];
  const int*   epoch = (const int*)d_in[2];
  float*       out   = (float*)d_out;

  uint*   glob_hist = (uint*)d_ws;
  double* ele       = (double*)((char*)d_ws + 8192);
  float*  prob      = (float*)((char*)d_ws + 8192 + T_ * HW_ * sizeof(double));

  hipMemsetAsync(d_ws, 0, 8192, stream);  // zero glob_hist (ws is poisoned 0xAA)

  k_hist_mi<<<HW_ / P_BLK, 256, 0, stream>>>(x, glob_hist, ele);
  k_glob_prob<<<1, 256, 0, stream>>>(glob_hist, ele, epoch, prob);

  const int n4 = (B_ * T_ * C_ * HW_) / 4;             // 4194304
  k_mask<<<n4 / 256, 256, 0, stream>>>((const float4*)x, (const float4*)noise,
                                       prob, (float4*)out);
}

// Round 2
// 212.620 us; speedup vs baseline: 1.9117x; 1.9117x over previous
//
#include <hip/hip_runtime.h>
#include <math.h>

// Problem constants (from reference setup_inputs):
//   x, noise: (b=16, t=8, c=32, h=64, w=64) float32, values in [0,16)
//   epoch: int scalar
#define B_   16
#define T_   8
#define C_   32
#define HW_  4096            // h*w
#define K_   16              // value bins
#define CHW_ (C_*HW_)        // 131072: stride between consecutive t for fixed (b,c)
#define BC_  (B_*C_)         // 512 samples per spatial element
#define P_BLK 8              // spatial positions per histogram workgroup

typedef unsigned int uint;

// ---------------------------------------------------------------------------
// Kernel P: pack the 8 temporal 4-bit values per (b,c,p) into one u32.
// packed[bc][p] = sum_t x[b][t][c][p] << (4t).  Reads x as float4 (coalesced),
// writes uint4 (coalesced). Grid 2048 blocks — fully parallel, memory-bound.
// ---------------------------------------------------------------------------
__global__ __launch_bounds__(256) void k_pack(const float4* __restrict__ x4,
                                              uint4* __restrict__ packed4) {
  const int n  = blockIdx.x * 256 + threadIdx.x;   // 0 .. 512*1024
  const int bc = n >> 10;                          // 0..511
  const int p4 = n & 1023;                         // float4 index within HW
  const int b  = bc >> 5;
  const int c  = bc & 31;
  uint4 acc = make_uint4(0u, 0u, 0u, 0u);
  #pragma unroll
  for (int t = 0; t < T_; ++t) {
    const float4 xv = x4[((b * T_ + t) * C_ + c) * (HW_ / 4) + p4];
    const int sh = 4 * t;
    acc.x |= ((uint)xv.x) << sh;
    acc.y |= ((uint)xv.y) << sh;
    acc.z |= ((uint)xv.z) << sh;
    acc.w |= ((uint)xv.w) << sh;
  }
  packed4[n] = acc;
}

// ---------------------------------------------------------------------------
// Kernel A: per-element joint histograms (t vs t=0) + per-element MI, and
// accumulate pooled (global) histograms via atomics.
// Grid: HW_/P_BLK = 512 blocks, 512 threads. LDS: 64KB hist + 4.1KB logtab
// -> 2 blocks/CU, 16 waves/CU.
// Bin rotation (bin + lp*37) & 255 spreads data-dependent bank collisions
// across lp slots (37 mod 32 = 5 -> 8 distinct bank offsets).
// MI identity:  MI = ln(n) + ( Σ c·ln c − Σ_a r_a·ln r_a − Σ_v col_v·ln col_v ) / n
// ---------------------------------------------------------------------------
__global__ __launch_bounds__(512) void k_hist_mi(const uint* __restrict__ packed,
                                                 uint* __restrict__ glob_hist,
                                                 double* __restrict__ ele) {
  __shared__ uint   hist[T_][P_BLK][256];   // 64 KB
  __shared__ double logtab[513];            // 4.1 KB

  const int tid = threadIdx.x;
  const int p0  = blockIdx.x * P_BLK;

  for (int i = tid; i < T_ * P_BLK * 256; i += 512) ((uint*)hist)[i] = 0u;
  for (int i = tid; i < 513; i += 512) logtab[i] = (i > 0) ? log((double)i) : 0.0;
  __syncthreads();

  const int lp  = tid & 7;    // which p within the block
  const int g   = tid >> 3;   // sample-group 0..63
  const int rot = lp * 37;

  // Preload all 8 packed words (independent -> all in flight at once).
  uint w[8];
  #pragma unroll
  for (int k = 0; k < 8; ++k)
    w[k] = packed[(g + (k << 6)) * HW_ + p0 + lp];

  #pragma unroll
  for (int k = 0; k < 8; ++k) {
    const uint wk  = w[k];
    const int  a   = (int)(wk & 15u);
    const int  row = a << 4;
    atomicAdd(&hist[0][lp][((row | a) + rot) & 255], 1u);   // t=0: joint(a,a)
    #pragma unroll
    for (int t = 1; t < T_; ++t) {
      const int v = (int)((wk >> (4 * t)) & 15u);
      atomicAdd(&hist[t][lp][((row | v) + rot) & 255], 1u);
    }
  }
  __syncthreads();

  // Pooled histograms: global joint = sum over p of per-element joints.
  for (int i = tid; i < T_ * 256; i += 512) {
    const int t = i >> 8, bin = i & 255;
    uint s = 0;
    #pragma unroll
    for (int p = 0; p < P_BLK; ++p) s += hist[t][p][(bin + p * 37) & 255];
    atomicAdd(&glob_hist[i], s);
  }

  // Per-element MI: one thread per (t, p) — 64 active threads.
  if (tid < T_ * P_BLK) {
    const int t    = tid >> 3;
    const int lpp  = tid & 7;
    const int rr   = lpp * 37;
    const uint* h  = &hist[t][lpp][0];
    double term = 0.0;
    #pragma unroll
    for (int a = 0; a < K_; ++a) {
      uint r = 0;
      #pragma unroll
      for (int v = 0; v < K_; ++v) {
        const uint cnt = h[(((a << 4) | v) + rr) & 255];
        r += cnt;
        term += (double)cnt * logtab[cnt];      // c·ln c  (logtab[0]=0)
      }
      term -= (double)r * logtab[r];            // r·ln r   (r ≤ 512)
    }
    #pragma unroll
    for (int v = 0; v < K_; ++v) {
      uint col = 0;
      #pragma unroll
      for (int a = 0; a < K_; ++a) col += h[(((a << 4) | v) + rr) & 255];
      term -= (double)col * logtab[col];        // col·ln col
    }
    ele[t * HW_ + p0 + lpp] = logtab[512] + term * (1.0 / 512.0);  // MI
  }
}

// ---------------------------------------------------------------------------
// Kernel B1: global MI per t from pooled histograms. One block, 256 threads:
// tid<128 -> one (t, row) each; tid>=128 -> one (t, col) each; LDS reduce.
// ---------------------------------------------------------------------------
__global__ __launch_bounds__(256) void k_glob(const uint* __restrict__ glob_hist,
                                              double* __restrict__ glob) {
  __shared__ double part[256];
  const int tid = threadIdx.x;

  if (tid < 128) {                       // rows: Σ c·ln c − r·ln r
    const int t = tid >> 4, a = tid & 15;
    const uint* h = glob_hist + t * 256 + (a << 4);
    double s = 0.0, r = 0.0;
    #pragma unroll
    for (int v = 0; v < K_; ++v) {
      const double cnt = (double)h[v];
      r += cnt;
      if (cnt > 0.0) s += cnt * log(cnt);
    }
    if (r > 0.0) s -= r * log(r);
    part[tid] = s;
  } else {                               // cols: − col·ln col
    const int t = (tid - 128) >> 4, v = (tid - 128) & 15;
    const uint* h = glob_hist + t * 256 + v;
    double col = 0.0;
    #pragma unroll
    for (int a = 0; a < K_; ++a) col += (double)h[a << 4];
    part[tid] = (col > 0.0) ? -col * log(col) : 0.0;
  }
  __syncthreads();

  if (tid < T_) {
    double term = 0.0;
    #pragma unroll
    for (int i = 0; i < 16; ++i)
      term += part[tid * 16 + i] + part[128 + tid * 16 + i];
    const double n = (double)BC_ * (double)HW_;   // 2097152
    glob[tid] = log(n) + term / n;
  }
}

// ---------------------------------------------------------------------------
// Kernel B2: prob[t][p] = clip((ele[t][p]*glob[t])/(ele[0][p]*glob[0])
//                              * epoch/200, 0, 1);  prob[0][*] = 0.
// Grid 32 blocks x 256 — fully parallel.
// ---------------------------------------------------------------------------
__global__ __launch_bounds__(256) void k_prob(const double* __restrict__ ele,
                                              const double* __restrict__ glob,
                                              const int* __restrict__ epoch_ptr,
                                              float* __restrict__ prob) {
  const int i = blockIdx.x * 256 + threadIdx.x;   // < 32768
  const int t = i >> 12;
  const int p = i & (HW_ - 1);
  float pv;
  if (t == 0) {
    pv = 0.0f;
  } else {
    const double escale = (double)(*epoch_ptr) * (1.0 / 200.0);
    const double mi0 = ele[p] * glob[0];
    const double mit = ele[i] * glob[t];
    const double v  = (mit / mi0) * escale;
    pv = fminf(fmaxf((float)v, 0.0f), 1.0f);
  }
  prob[i] = pv;
}

// ---------------------------------------------------------------------------
// Kernel C: out = (noise < prob[t][p]) ? 0 : x.  float4 vectorized.
// ---------------------------------------------------------------------------
__global__ __launch_bounds__(256) void k_mask(const float4* __restrict__ x4,
                                              const float4* __restrict__ n4,
                                              const float* __restrict__ prob,
                                              float4* __restrict__ o4) {
  const int i = blockIdx.x * 256 + threadIdx.x;        // float4 index
  const int t = (i >> 15) & 7;                         // (4i / 131072) % 8
  const float4 pr = ((const float4*)prob)[(t << 10) | (i & 1023)];
  const float4 xv = x4[i];
  const float4 nv = n4[i];
  float4 o;
  o.x = (nv.x < pr.x) ? 0.0f : xv.x;
  o.y = (nv.y < pr.y) ? 0.0f : xv.y;
  o.z = (nv.z < pr.z) ? 0.0f : xv.z;
  o.w = (nv.w < pr.w) ? 0.0f : xv.w;
  o4[i] = o;
}

// ---------------------------------------------------------------------------
// Workspace layout:
//   [0, 8KB)                  glob_hist : u32[8][256]   (memset to 0 each call)
//   [8KB, 8KB+8MB)            packed    : u32[512][4096]
//   [+8MB, +256KB)            ele       : f64[8][4096]
//   [+256KB, +64B)            glob      : f64[8]
//   [+64B, +128KB)            prob      : f32[8][4096]
// ---------------------------------------------------------------------------
extern "C" void kernel_launch(void* const* d_in, const int* in_sizes, int n_in,
                              void* d_out, int out_size, void* d_ws, size_t ws_size,
                              hipStream_t stream) {
  const float* x     = (const float*)d_in[0];
  const float* noise = (const float*)d_in[1];
  const int*   epoch = (const int*)d_in[2];
  float*       out   = (float*)d_out;

  char* ws = (char*)d_ws;
  uint*   glob_hist = (uint*)ws;                                  // 8 KB
  uint*   packed    = (uint*)(ws + 8192);                         // 8 MB
  double* ele       = (double*)(ws + 8192 + (size_t)BC_ * HW_ * 4);        // 256 KB
  double* glob      = (double*)((char*)ele + (size_t)T_ * HW_ * 8);        // 64 B
  float*  prob      = (float*)((char*)glob + 64);                          // 128 KB

  hipMemsetAsync(glob_hist, 0, 8192, stream);  // ws is poisoned 0xAA

  k_pack<<<(BC_ * HW_ / 4) / 256, 256, 0, stream>>>((const float4*)x,
                                                    (uint4*)packed);
  k_hist_mi<<<HW_ / P_BLK, 512, 0, stream>>>(packed, glob_hist, ele);
  k_glob<<<1, 256, 0, stream>>>(glob_hist, glob);
  k_prob<<<(T_ * HW_) / 256, 256, 0, stream>>>(ele, glob, epoch, prob);

  const int n4 = (B_ * T_ * C_ * HW_) / 4;             // 4194304
  k_mask<<<n4 / 256, 256, 0, stream>>>((const float4*)x, (const float4*)noise,
                                       prob, (float4*)out);
}

// Round 5
// 208.842 us; speedup vs baseline: 1.9463x; 1.0181x over previous
//
#include <hip/hip_runtime.h>
#include <math.h>

// Problem constants (from reference setup_inputs):
//   x, noise: (b=16, t=8, c=32, h=64, w=64) float32, values in [0,16)
//   epoch: int scalar
#define B_   16
#define T_   8
#define C_   32
#define HW_  4096            // h*w
#define K_   16              // value bins
#define BC_  (B_*C_)         // 512 samples per spatial element
#define P_BLK 8              // spatial positions per histogram workgroup

typedef unsigned int uint;

// ---------------------------------------------------------------------------
// Kernel P: pack the 8 temporal 4-bit values per (b,c,p) into one u32.
// packed[bc][p] = sum_t x[b][t][c][p] << (4t).  Reads x as float4 (coalesced),
// writes uint4 (coalesced). Block 0 also zeroes glob_hist (replaces memset;
// safe: glob_hist is only touched by k_hist_mi, which is stream-ordered after).
// ---------------------------------------------------------------------------
__global__ __launch_bounds__(256) void k_pack(const float4* __restrict__ x4,
                                              uint4* __restrict__ packed4,
                                              uint4* __restrict__ glob_hist4) {
  const int tid = threadIdx.x;
  if (blockIdx.x == 0) {                       // zero u32[8][256] = 512 uint4
    const uint4 z = make_uint4(0u, 0u, 0u, 0u);
    glob_hist4[tid] = z;
    glob_hist4[tid + 256] = z;
  }
  const int n  = blockIdx.x * 256 + tid;       // 0 .. 512*1024
  const int bc = n >> 10;                      // 0..511
  const int p4 = n & 1023;                     // float4 index within HW
  const int b  = bc >> 5;
  const int c  = bc & 31;
  uint4 acc = make_uint4(0u, 0u, 0u, 0u);
  #pragma unroll
  for (int t = 0; t < T_; ++t) {
    const float4 xv = x4[((b * T_ + t) * C_ + c) * (HW_ / 4) + p4];
    const int sh = 4 * t;
    acc.x |= ((uint)xv.x) << sh;
    acc.y |= ((uint)xv.y) << sh;
    acc.z |= ((uint)xv.z) << sh;
    acc.w |= ((uint)xv.w) << sh;
  }
  packed4[n] = acc;
}

// ---------------------------------------------------------------------------
// Kernel A: per-element joint histograms (t vs t=0) + per-element MI, and
// accumulate pooled (global) histograms via atomics.
// Grid: HW_/P_BLK = 512 blocks x 512 threads. LDS: 64KB hist + 4.1KB logtab.
// Bin rotation (bin + lp*37) & 255 spreads data-dependent bank collisions.
// MI identity:  MI = ln(n) + ( Σ c·ln c − Σ_a r_a·ln r_a − Σ_v col_v·ln col_v ) / n
// MI tail is wave-parallel: wave wid owns t=wid, sweeps p=0..7; 64 lanes split
// the 256 cells (4 each), lanes 0..15 do row sums, 16..31 col sums, f64
// shuffle-tree reduce.
// ---------------------------------------------------------------------------
__global__ __launch_bounds__(512) void k_hist_mi(const uint* __restrict__ packed,
                                                 uint* __restrict__ glob_hist,
                                                 double* __restrict__ ele) {
  __shared__ uint   hist[T_][P_BLK][256];   // 64 KB
  __shared__ double logtab[513];            // 4.1 KB

  const int tid = threadIdx.x;
  const int p0  = blockIdx.x * P_BLK;

  for (int i = tid; i < T_ * P_BLK * 256; i += 512) ((uint*)hist)[i] = 0u;
  for (int i = tid; i < 513; i += 512) logtab[i] = (i > 0) ? log((double)i) : 0.0;
  __syncthreads();

  const int lp  = tid & 7;    // which p within the block
  const int g   = tid >> 3;   // sample-group 0..63
  const int rot = lp * 37;

  // Preload all 8 packed words (independent -> all in flight at once).
  uint w[8];
  #pragma unroll
  for (int k = 0; k < 8; ++k)
    w[k] = packed[(g + (k << 6)) * HW_ + p0 + lp];

  #pragma unroll
  for (int k = 0; k < 8; ++k) {
    const uint wk  = w[k];
    const int  a   = (int)(wk & 15u);
    const int  row = a << 4;
    atomicAdd(&hist[0][lp][((row | a) + rot) & 255], 1u);   // t=0: joint(a,a)
    #pragma unroll
    for (int t = 1; t < T_; ++t) {
      const int v = (int)((wk >> (4 * t)) & 15u);
      atomicAdd(&hist[t][lp][((row | v) + rot) & 255], 1u);
    }
  }
  __syncthreads();

  // Pooled histograms: global joint = sum over p of per-element joints.
  for (int i = tid; i < T_ * 256; i += 512) {
    const int t = i >> 8, bin = i & 255;
    uint s = 0;
    #pragma unroll
    for (int p = 0; p < P_BLK; ++p) s += hist[t][p][(bin + p * 37) & 255];
    atomicAdd(&glob_hist[i], s);
  }
  // (hist is read-only from here; no extra barrier needed)

  // Wave-parallel per-element MI.
  const int wid  = tid >> 6;   // wave id = t
  const int lane = tid & 63;
  #pragma unroll
  for (int p = 0; p < P_BLK; ++p) {
    const uint* h = &hist[wid][p][0];
    const int   rr = p * 37;
    // cells: lane handles linear j = lane*4 .. +3  ->  Σ c·ln c  partial
    double acc = 0.0;
    #pragma unroll
    for (int j0 = 0; j0 < 4; ++j0) {
      const uint cnt = h[((lane << 2) + j0 + rr) & 255];
      acc += (double)cnt * logtab[cnt];
    }
    // marginals: lanes 0..15 rows (−r·ln r), lanes 16..31 cols (−col·ln col)
    if (lane < 16) {
      uint r = 0;
      #pragma unroll
      for (int v = 0; v < K_; ++v) r += h[(((lane << 4) | v) + rr) & 255];
      acc -= (double)r * logtab[r];
    } else if (lane < 32) {
      const int v = lane - 16;
      uint col = 0;
      #pragma unroll
      for (int a = 0; a < K_; ++a) col += h[(((a << 4) | v) + rr) & 255];
      acc -= (double)col * logtab[col];
    }
    // f64 butterfly reduce over the wave
    #pragma unroll
    for (int m = 1; m < 64; m <<= 1) acc += __shfl_xor(acc, m, 64);
    if (lane == 0)
      ele[wid * HW_ + p0 + p] = logtab[512] + acc * (1.0 / 512.0);
  }
}

// ---------------------------------------------------------------------------
// Kernel B: pooled (global) MI per t + prob. 32 blocks x 256 threads; each
// block redundantly computes glob[8] (cheap), then its 1024 prob entries.
// prob[t][p] = clip((ele[t][p]*glob[t])/(ele[0][p]*glob[0]) * epoch/200, 0, 1)
// prob[0][*] = 0.
// ---------------------------------------------------------------------------
__global__ __launch_bounds__(256) void k_glob_prob(const uint* __restrict__ glob_hist,
                                                   const double* __restrict__ ele,
                                                   const int* __restrict__ epoch_ptr,
                                                   float* __restrict__ prob) {
  __shared__ double part[256];
  __shared__ double glob[T_];
  const int tid = threadIdx.x;

  if (tid < 128) {                       // rows: Σ c·ln c − r·ln r
    const int t = tid >> 4, a = tid & 15;
    const uint* h = glob_hist + t * 256 + (a << 4);
    double s = 0.0, r = 0.0;
    #pragma unroll
    for (int v = 0; v < K_; ++v) {
      const double cnt = (double)h[v];
      r += cnt;
      if (cnt > 0.0) s += cnt * log(cnt);
    }
    if (r > 0.0) s -= r * log(r);
    part[tid] = s;
  } else {                               // cols: − col·ln col
    const int t = (tid - 128) >> 4, v = (tid - 128) & 15;
    const uint* h = glob_hist + t * 256 + v;
    double col = 0.0;
    #pragma unroll
    for (int a = 0; a < K_; ++a) col += (double)h[a << 4];
    part[tid] = (col > 0.0) ? -col * log(col) : 0.0;
  }
  __syncthreads();

  if (tid < T_) {
    double term = 0.0;
    #pragma unroll
    for (int i = 0; i < 16; ++i)
      term += part[tid * 16 + i] + part[128 + tid * 16 + i];
    const double n = (double)BC_ * (double)HW_;   // 2097152
    glob[tid] = log(n) + term / n;
  }
  __syncthreads();

  const double escale = (double)(*epoch_ptr) * (1.0 / 200.0);
  #pragma unroll
  for (int k = 0; k < 4; ++k) {
    const int i = blockIdx.x * 1024 + k * 256 + tid;   // < 32768
    const int t = i >> 12;
    const int p = i & (HW_ - 1);
    float pv = 0.0f;
    if (t != 0) {
      const double mi0 = ele[p] * glob[0];
      const double mit = ele[i] * glob[t];
      const double v  = (mit / mi0) * escale;
      pv = fminf(fmaxf((float)v, 0.0f), 1.0f);
    }
    prob[i] = pv;
  }
}

// ---------------------------------------------------------------------------
// Kernel C: out = (noise < prob[t][p]) ? 0 : x, where x is reconstructed from
// packed (values are exact 4-bit ints) — saves the 64MB x re-read.
// Traffic: packed 8MB (L2/L3) + noise 64MB + out 64MB.
// ---------------------------------------------------------------------------
__global__ __launch_bounds__(256) void k_mask(const uint4* __restrict__ packed4,
                                              const float4* __restrict__ n4,
                                              const float* __restrict__ prob,
                                              float4* __restrict__ o4) {
  const int i  = blockIdx.x * 256 + threadIdx.x;   // float4 index, < 4194304
  const int p4 = i & 1023;
  const int tc = i >> 10;          // (b*T + t)*C + c
  const int c  = tc & 31;
  const int bt = tc >> 5;          // b*T + t
  const int t  = bt & 7;
  const int b  = bt >> 3;
  const uint4 pk = packed4[(((b << 5) | c) << 10) | p4];
  const int sh = 4 * t;
  float4 xv;
  xv.x = (float)((pk.x >> sh) & 15u);
  xv.y = (float)((pk.y >> sh) & 15u);
  xv.z = (float)((pk.z >> sh) & 15u);
  xv.w = (float)((pk.w >> sh) & 15u);
  const float4 pr = ((const float4*)prob)[(t << 10) | p4];
  const float4 nv = n4[i];
  float4 o;
  o.x = (nv.x < pr.x) ? 0.0f : xv.x;
  o.y = (nv.y < pr.y) ? 0.0f : xv.y;
  o.z = (nv.z < pr.z) ? 0.0f : xv.z;
  o.w = (nv.w < pr.w) ? 0.0f : xv.w;
  o4[i] = o;
}

// ---------------------------------------------------------------------------
// Workspace layout:
//   [0, 8KB)                  glob_hist : u32[8][256]   (zeroed by k_pack blk 0)
//   [8KB, 8KB+8MB)            packed    : u32[512][4096]
//   [+8MB, +256KB)            ele       : f64[8][4096]
//   [+256KB, +128KB)          prob      : f32[8][4096]
// ---------------------------------------------------------------------------
extern "C" void kernel_launch(void* const* d_in, const int* in_sizes, int n_in,
                              void* d_out, int out_size, void* d_ws, size_t ws_size,
                              hipStream_t stream) {
  const float* x     = (const float*)d_in[0];
  const float* noise = (const float*)d_in[1];
  const int*   epoch = (const int*)d_in[2];
  float*       out   = (float*)d_out;

  char* ws = (char*)d_ws;
  uint*   glob_hist = (uint*)ws;                                         // 8 KB
  uint*   packed    = (uint*)(ws + 8192);                                // 8 MB
  double* ele       = (double*)(ws + 8192 + (size_t)BC_ * HW_ * 4);      // 256 KB
  float*  prob      = (float*)((char*)ele + (size_t)T_ * HW_ * 8);       // 128 KB

  k_pack<<<(BC_ * HW_ / 4) / 256, 256, 0, stream>>>((const float4*)x,
                                                    (uint4*)packed,
                                                    (uint4*)glob_hist);
  k_hist_mi<<<HW_ / P_BLK, 512, 0, stream>>>(packed, glob_hist, ele);
  k_glob_prob<<<32, 256, 0, stream>>>(glob_hist, ele, epoch, prob);

  const int n4 = (B_ * T_ * C_ * HW_) / 4;             // 4194304
  k_mask<<<n4 / 256, 256, 0, stream>>>((const uint4*)packed,
                                       (const float4*)noise,
                                       prob, (float4*)out);
}